// Round 6
// baseline (370.194 us; speedup 1.0000x reference)
//
#include <hip/hip_runtime.h>
#include <math.h>
#include <stdint.h>

// ---------------------------------------------------------------------------
// TransFrame: B=2, H=W=128, D=8, C=64 ; F_IN=F_OUT=512 ; HEADS=4, Dh=128
// Round-6:
//   - qk_gram: BK=32 double-buffered 2-phase pipeline, swizzle CORRECTED.
//     Round-3's X(r)=(r&3) made slot correlate with row parity -> 4-way bank
//     conflict (4.26M). X(r)=((r>>1)&3) spreads 16 rows over all 8 16B bank
//     slots x2 lanes = conflict-free. Same barrier/ds_read/MFMA counts as
//     BK=64, but stage(t+1) issues BEFORE compute(t) -> load latency hidden.
//   - dwconv direct-gather, fast_gelu, convert_x-8 kept from round 5.
// ---------------------------------------------------------------------------

using short8  = __attribute__((ext_vector_type(8))) short;
using f32x4   = __attribute__((ext_vector_type(4))) float;

__device__ __forceinline__ float bf2f(unsigned short u) {
  union { unsigned int i; float f; } v; v.i = ((unsigned int)u) << 16; return v.f;
}
__device__ __forceinline__ unsigned short f2bf(float f) {
  union { float f; unsigned int i; } v; v.f = f;
  unsigned int r = v.i + 0x7fffu + ((v.i >> 16) & 1u);
  return (unsigned short)(r >> 16);
}

__device__ __forceinline__ void g2l16(const void* g, void* l) {
  __builtin_amdgcn_global_load_lds(
      (__attribute__((address_space(1))) void*)(unsigned long long)(uintptr_t)g,
      (__attribute__((address_space(3))) void*)(unsigned int)(uintptr_t)l,
      16, 0, 0);
}

// GELU with A&S 7.1.26 erf approximation (|err| <= 1.5e-7, branch-free).
__device__ __forceinline__ float fast_gelu(float x) {
  float y = fabsf(x) * 0.70710678118654752f;
  float t = __builtin_amdgcn_rcpf(1.0f + 0.3275911f * y);
  float p = ((((1.061405429f * t - 1.453152027f) * t + 1.421413741f) * t
              - 0.284496736f) * t + 0.254829592f) * t;
  float er = 1.0f - p * __expf(-y * y);
  er = copysignf(er, x);
  return 0.5f * x * (1.0f + er);
}

// ---------------------------------------------------------------------------
__global__ __launch_bounds__(256) void convert_x(const float* __restrict__ x,
                                                 unsigned short* __restrict__ xb) {
  int i = (blockIdx.x * 256 + threadIdx.x) * 8;
  float4 a = *(const float4*)&x[i];
  float4 b = *(const float4*)&x[i + 4];
  ushort4 o0, o1;
  o0.x = f2bf(a.x); o0.y = f2bf(a.y); o0.z = f2bf(a.z); o0.w = f2bf(a.w);
  o1.x = f2bf(b.x); o1.y = f2bf(b.y); o1.z = f2bf(b.z); o1.w = f2bf(b.w);
  uint4 o; 
  o.x = *(unsigned*)&o0.x; o.y = *(unsigned*)&o0.z;
  o.z = *(unsigned*)&o1.x; o.w = *(unsigned*)&o1.z;
  *(uint4*)&xb[i] = o;
}

__global__ __launch_bounds__(256) void prep_w(const float* __restrict__ Wq,
                                              const float* __restrict__ Wk,
                                              const float* __restrict__ Wv,
                                              const float* __restrict__ Wp,
                                              unsigned short* __restrict__ Wcat_t,
                                              unsigned short* __restrict__ Wp_t) {
  __shared__ unsigned short Ls[32 * 36];
  int bid = blockIdx.x;
  int mat = bid >> 8, tile = bid & 255;
  int tr = (tile >> 4) * 32, tc = (tile & 15) * 32;
  const float* src = (mat == 0) ? Wq : (mat == 1) ? Wk : (mat == 2) ? Wv : Wp;
  int t = threadIdx.x;
  int r = t >> 3, c4 = (t & 7) * 4;
  float4 v = *(const float4*)&src[(tr + r) * 512 + tc + c4];
  Ls[(c4 + 0) * 36 + r] = f2bf(v.x);
  Ls[(c4 + 1) * 36 + r] = f2bf(v.y);
  Ls[(c4 + 2) * 36 + r] = f2bf(v.z);
  Ls[(c4 + 3) * 36 + r] = f2bf(v.w);
  __syncthreads();
  int rn = t >> 3, ck4 = (t & 7) * 4;
  ushort4 o;
  o.x = Ls[rn * 36 + ck4 + 0]; o.y = Ls[rn * 36 + ck4 + 1];
  o.z = Ls[rn * 36 + ck4 + 2]; o.w = Ls[rn * 36 + ck4 + 3];
  unsigned short* dst = (mat < 3)
      ? &Wcat_t[(long)(mat * 512 + tc + rn) * 512 + tr + ck4]
      : &Wp_t[(long)(tc + rn) * 512 + tr + ck4];
  *(ushort4*)dst = o;
}

// ---------------------------------------------------------------------------
// qk_gram: grid (mt2=64, h=4, b=2). Each block: two 128-row m-tiles.
// BK=32 dbuf (2 x {A,Bq,Bk} x 8KB = 48KB staging), 2-phase pipeline,
// conflict-free swizzle X(r) = (r>>1)&3.
// Epilogue overlay (kT/qT/red) sets the 77.8KB LDS block (2 blocks/CU).
// ---------------------------------------------------------------------------
__global__ __launch_bounds__(256, 2) void qk_gram(
    const unsigned short* __restrict__ x_bf,
    const unsigned short* __restrict__ Wcat_t,
    float* __restrict__ Gp, float* __restrict__ ss) {
  __shared__ unsigned short sh[38912];   // 77,824 B
  const int mt2 = blockIdx.x, h = blockIdx.y, b = blockIdx.z;
  const int t = threadIdx.x;
  const int lane = t & 63, w = t >> 6;
  const int wm = w >> 1, wn = w & 1;
  const int quad = lane >> 4, l16 = lane & 15;
  const int sr2 = lane >> 2, sc2 = lane & 3;   // staging: 16 rows x 4 slots of 8
  const unsigned short* Bq = Wcat_t + (long)(h * 128) * 512;
  const unsigned short* Bk = Wcat_t + (long)(512 + h * 128) * 512;

  f32x4 g[4][4] = {};   // persistent gram accumulator across both halves

  for (int half = 0; half < 2; half++) {
    const unsigned short* A = x_bf + ((long)b * 16384 + (mt2 * 2 + half) * 128) * 512;
    f32x4 aq[4][4] = {}, ak[4][4] = {};

    // stage one BK=32 K-slice into buffer d (each tile 128x32 = 8KB)
    auto stage = [&](int k0, int d) {
      unsigned short* Sa = sh + d * 12288;
      unsigned short* Sq = Sa + 4096;
      unsigned short* Sk = Sa + 8192;
#pragma unroll
      for (int q = 0; q < 2; q++) {
        int r = q * 64 + w * 16 + sr2;
        int ca = (sc2 ^ ((sr2 >> 1) & 3)) * 8;   // conflict-free swizzle source
        long off = (long)r * 512 + k0 + ca;
        int ldsb = (q * 64 + w * 16) * 32;
        g2l16(&A[off],  &Sa[ldsb]);
        g2l16(&Bq[off], &Sq[ldsb]);
        g2l16(&Bk[off], &Sk[ldsb]);
      }
    };

    stage(0, 0);
    __syncthreads();
    for (int ks = 0; ks < 16; ks++) {
      int d = ks & 1;
      if (ks < 15) stage((ks + 1) * 32, d ^ 1);   // prefetch next slice
      const unsigned short* Sa = sh + d * 12288;
      const unsigned short* Sq = Sa + 4096;
      const unsigned short* Sk = Sa + 8192;
      short8 af[4], bq4[4], bk4[4];
#pragma unroll
      for (int i = 0; i < 4; i++) {
        int r = wm * 64 + i * 16 + l16;
        int s = quad ^ ((r >> 1) & 3);
        af[i] = *(const short8*)&Sa[r * 32 + s * 8];
      }
#pragma unroll
      for (int j = 0; j < 4; j++) {
        int r = wn * 64 + j * 16 + l16;
        int s = quad ^ ((r >> 1) & 3);
        bq4[j] = *(const short8*)&Sq[r * 32 + s * 8];
        bk4[j] = *(const short8*)&Sk[r * 32 + s * 8];
      }
#pragma unroll
      for (int i = 0; i < 4; i++)
#pragma unroll
        for (int j = 0; j < 4; j++) {
          aq[i][j] = __builtin_amdgcn_mfma_f32_16x16x32_bf16(af[i], bq4[j], aq[i][j], 0, 0, 0);
          ak[i][j] = __builtin_amdgcn_mfma_f32_16x16x32_bf16(af[i], bk4[j], ak[i][j], 0, 0, 0);
        }
      __syncthreads();   // drains prefetch vmcnt (hidden under compute above)
    }

    // epilogue: aq[i][j][r] = q[m=wm*64+i*16+quad*4+r][f=wn*64+j*16+l16]
    unsigned short* kT = sh;           // 128 x 136
    unsigned short* qT = sh + 17408;   // 128 x 136
    float* red = (float*)(sh + 34816); // 2048 floats: [0..1023]=q, [1024..]=k
#pragma unroll
    for (int i = 0; i < 4; i++) {
      int mm = wm * 64 + i * 16 + quad * 4;
#pragma unroll
      for (int j = 0; j < 4; j++) {
        int f = wn * 64 + j * 16 + l16;
        ushort4 oq = { f2bf(aq[i][j][0]), f2bf(aq[i][j][1]), f2bf(aq[i][j][2]), f2bf(aq[i][j][3]) };
        ushort4 ok = { f2bf(ak[i][j][0]), f2bf(ak[i][j][1]), f2bf(ak[i][j][2]), f2bf(ak[i][j][3]) };
        *(ushort4*)&qT[f * 136 + mm] = oq;
        *(ushort4*)&kT[f * 136 + mm] = ok;
      }
    }
    // sumsq partials (pre-rounding fp32 acc)
    int grp = wm * 4 + quad;
#pragma unroll
    for (int j = 0; j < 4; j++) {
      float pq = 0.f, pk = 0.f;
#pragma unroll
      for (int i = 0; i < 4; i++)
#pragma unroll
        for (int r = 0; r < 4; r++) { pq += aq[i][j][r] * aq[i][j][r]; pk += ak[i][j][r] * ak[i][j][r]; }
      int col = wn * 64 + j * 16 + l16;
      red[grp * 128 + col] = pq;
      red[1024 + grp * 128 + col] = pk;
    }
    __syncthreads();
    // gram: G[d][e] += sum_m kT[d][m]*qT[e][m], m=0..127 (4 chunks of 32)
#pragma unroll
    for (int kk2 = 0; kk2 < 4; kk2++) {
      short8 afk[4], bfq[4];
#pragma unroll
      for (int i = 0; i < 4; i++)
        afk[i] = *(const short8*)&kT[(wm * 64 + i * 16 + l16) * 136 + kk2 * 32 + quad * 8];
#pragma unroll
      for (int j = 0; j < 4; j++)
        bfq[j] = *(const short8*)&qT[(wn * 64 + j * 16 + l16) * 136 + kk2 * 32 + quad * 8];
#pragma unroll
      for (int i = 0; i < 4; i++)
#pragma unroll
        for (int j = 0; j < 4; j++)
          g[i][j] = __builtin_amdgcn_mfma_f32_16x16x32_bf16(afk[i], bfq[j], g[i][j], 0, 0, 0);
    }
    // finish sumsq for this half
    {
      int sel = t >> 7, col = t & 127;
      float s = 0.f;
#pragma unroll
      for (int g2 = 0; g2 < 8; g2++) s += red[sel * 1024 + g2 * 128 + col];
      atomicAdd(&ss[b * 1024 + sel * 512 + h * 128 + col], s);
    }
    __syncthreads();   // protect kT/qT/red until all reads done before next half's staging
  }

  // store transposed partial: Gt[e][d] (d consecutive in lane -> f32x4)
  float* gp = Gp + (((long)(b * 64 + mt2) * 4 + h) << 14);
#pragma unroll
  for (int i = 0; i < 4; i++) {
    int dd = wm * 64 + i * 16 + quad * 4;
#pragma unroll
    for (int j = 0; j < 4; j++) {
      int e = wn * 64 + j * 16 + l16;
      *(f32x4*)&gp[e * 128 + dd] = g[i][j];
    }
  }
}

// ---------------------------------------------------------------------------
// v_gemm: grid (mt=128, nt=4, b=2). v n-tile, swapped-operand epilogue.
// ---------------------------------------------------------------------------
__global__ __launch_bounds__(256, 3) void v_gemm(
    const unsigned short* __restrict__ x_bf,
    const unsigned short* __restrict__ Wcat_t,
    unsigned short* __restrict__ v) {
  __shared__ unsigned short As[8192];
  __shared__ unsigned short Bs[8192];
  const int mt = blockIdx.x, nt = blockIdx.y, b = blockIdx.z;
  const int t = threadIdx.x;
  const int lane = t & 63, w = t >> 6;
  const int wm = w >> 1, wn = w & 1;
  const int quad = lane >> 4, l16 = lane & 15;
  const int sr = lane >> 3, sc = lane & 7;
  const unsigned short* A  = x_bf + ((long)b * 16384 + mt * 128) * 512;
  const unsigned short* Bt = Wcat_t + (long)(1024 + nt * 128) * 512;

  f32x4 acc[4][4] = {};
  for (int k0 = 0; k0 < 512; k0 += 64) {
#pragma unroll
    for (int q = 0; q < 4; q++) {
      int r = q * 32 + w * 8 + sr;
      int ca = (sc ^ sr) * 8;
      g2l16(&A[(long)r * 512 + k0 + ca],  &As[(q * 32 + w * 8) * 64]);
      g2l16(&Bt[(long)r * 512 + k0 + ca], &Bs[(q * 32 + w * 8) * 64]);
    }
    __syncthreads();
#pragma unroll
    for (int kk = 0; kk < 2; kk++) {
      short8 af[4], bf[4];
#pragma unroll
      for (int i = 0; i < 4; i++) {
        int r = wm * 64 + i * 16 + l16;
        int s = (kk * 4 + quad) ^ (r & 7);
        af[i] = *(const short8*)&As[r * 64 + s * 8];
      }
#pragma unroll
      for (int j = 0; j < 4; j++) {
        int r = wn * 64 + j * 16 + l16;
        int s = (kk * 4 + quad) ^ (r & 7);
        bf[j] = *(const short8*)&Bs[r * 64 + s * 8];
      }
#pragma unroll
      for (int i = 0; i < 4; i++)
#pragma unroll
        for (int j = 0; j < 4; j++)
          acc[i][j] = __builtin_amdgcn_mfma_f32_16x16x32_bf16(bf[j], af[i], acc[i][j], 0, 0, 0);
    }
    __syncthreads();
  }
  unsigned short* vout = v + ((long)b * 16384 + mt * 128) * 512 + nt * 128;
#pragma unroll
  for (int i = 0; i < 4; i++) {
    long rbase = (long)(wm * 64 + i * 16 + l16) * 512;
#pragma unroll
    for (int j = 0; j < 4; j++) {
      int col = wn * 64 + j * 16 + quad * 4;
      uint2 o;
      o.x = (unsigned)f2bf(acc[i][j][0]) | ((unsigned)f2bf(acc[i][j][1]) << 16);
      o.y = (unsigned)f2bf(acc[i][j][2]) | ((unsigned)f2bf(acc[i][j][3]) << 16);
      *(uint2*)&vout[rbase + col] = o;
    }
  }
}

// G(t)[b,h][e][d] = sum over 64 mt2-tiles of Gp
__global__ __launch_bounds__(256) void reduce_g(const float* __restrict__ Gp,
                                                float* __restrict__ G) {
  int i = blockIdx.x * 256 + threadIdx.x;
  int b = i >> 16, h = (i >> 14) & 3, r = i & 16383;
  const float* p = Gp + (((long)b * 256 + h) << 14) + r;
  float s = 0.f;
#pragma unroll 8
  for (int mtv = 0; mtv < 64; mtv++) s += p[(long)mtv * 65536];
  G[i] = s;
}

// ---------------------------------------------------------------------------
// softmax over e of scaled G (input is Gt[e][d]); writes block-diag Abd.
// ---------------------------------------------------------------------------
__global__ __launch_bounds__(256) void softmax_kernel(const float* __restrict__ Gt,
                                                      const float* __restrict__ ss,
                                                      const float* __restrict__ rescale,
                                                      unsigned short* __restrict__ Abd) {
  __shared__ float L[128 * 129];
  __shared__ float rsq[128];
  __shared__ float rsk[128];
  int h = blockIdx.x, b = blockIdx.y;
  int t = threadIdx.x;
  const float* g = Gt + (long)(b * 4 + h) * 16384;
  if (t < 128) rsq[t] = rsqrtf(fmaxf(ss[b * 1024 + h * 128 + t], 1e-24f));
  else { int d = t - 128; rsk[d] = rsqrtf(fmaxf(ss[b * 1024 + 512 + h * 128 + d], 1e-24f)); }
  __syncthreads();
  float rs = rescale[h];
  for (int i = t; i < 16384; i += 256) {
    int e = i >> 7, d = i & 127;           // Gt is e-major
    L[d * 129 + e] = g[i] * rsk[d] * rsq[e] * rs;
  }
  __syncthreads();
  if (t < 128) {
    float* row = &L[t * 129];
    float mx = -1e30f;
    for (int e = 0; e < 128; e++) mx = fmaxf(mx, row[e]);
    float sum = 0.0f;
    for (int e = 0; e < 128; e++) { float ex = __expf(row[e] - mx); row[e] = ex; sum += ex; }
    float inv = 1.0f / sum;
    long abase = (long)b * 262144;
    for (int e = 0; e < 128; e++)
      Abd[abase + (long)(h * 128 + e) * 512 + h * 128 + t] = f2bf(row[e] * inv);
  }
}

// ---------------------------------------------------------------------------
// generic bf16 GEMM: C=A@Bt^T (+bias), swapped epilogue.
// ---------------------------------------------------------------------------
__global__ __launch_bounds__(256, 3) void gemm_lds(
    const unsigned short* __restrict__ A, const unsigned short* __restrict__ Bt,
    unsigned short* __restrict__ C, const float* __restrict__ bias,
    int lda, int ldb, int ldc, int K, long sA, long sB, long sC) {
  __shared__ unsigned short As[128 * 64];
  __shared__ unsigned short Bs[128 * 64];
  const int t = threadIdx.x;
  const int m0 = blockIdx.x * 128, n0 = blockIdx.y * 128;
  A  += (long)blockIdx.z * sA + (long)m0 * lda;
  Bt += (long)blockIdx.z * sB + (long)n0 * ldb;
  C  += (long)blockIdx.z * sC;
  const int lane = t & 63, w = t >> 6;
  const int wm = w >> 1, wn = w & 1;
  const int quad = lane >> 4, l16 = lane & 15;
  const int sr = lane >> 3, sc = lane & 7;

  f32x4 acc[4][4] = {};

  for (int k0 = 0; k0 < K; k0 += 64) {
#pragma unroll
    for (int q = 0; q < 4; q++) {
      int r = q * 32 + w * 8 + sr;
      int ca = (sc ^ sr) * 8;
      g2l16(&A[(long)r * lda + k0 + ca], &As[(q * 32 + w * 8) * 64]);
      g2l16(&Bt[(long)r * ldb + k0 + ca], &Bs[(q * 32 + w * 8) * 64]);
    }
    __syncthreads();
#pragma unroll
    for (int kk = 0; kk < 2; kk++) {
      short8 af[4], bfq[4];
#pragma unroll
      for (int i = 0; i < 4; i++) {
        int r = wm * 64 + i * 16 + l16;
        int s = (kk * 4 + quad) ^ (r & 7);
        af[i] = *(const short8*)&As[r * 64 + s * 8];
      }
#pragma unroll
      for (int j = 0; j < 4; j++) {
        int r = wn * 64 + j * 16 + l16;
        int s = (kk * 4 + quad) ^ (r & 7);
        bfq[j] = *(const short8*)&Bs[r * 64 + s * 8];
      }
#pragma unroll
      for (int i = 0; i < 4; i++)
#pragma unroll
        for (int j = 0; j < 4; j++)
          acc[i][j] = __builtin_amdgcn_mfma_f32_16x16x32_bf16(bfq[j], af[i], acc[i][j], 0, 0, 0);
    }
    __syncthreads();
  }

#pragma unroll
  for (int i = 0; i < 4; i++) {
    long rbase = (long)(m0 + wm * 64 + i * 16 + l16) * ldc;
#pragma unroll
    for (int j = 0; j < 4; j++) {
      int col = n0 + wn * 64 + j * 16 + quad * 4;
      float b0 = 0.f, b1 = 0.f, b2 = 0.f, b3 = 0.f;
      if (bias) { float4 bv = *(const float4*)&bias[col]; b0 = bv.x; b1 = bv.y; b2 = bv.z; b3 = bv.w; }
      uint2 o;
      o.x = (unsigned)f2bf(acc[i][j][0] + b0) | ((unsigned)f2bf(acc[i][j][1] + b1) << 16);
      o.y = (unsigned)f2bf(acc[i][j][2] + b2) | ((unsigned)f2bf(acc[i][j][3] + b3) << 16);
      *(uint2*)&C[rbase + col] = o;
    }
  }
}

// ---------------------------------------------------------------------------
// depthwise 3x3x3 conv, direct-gather version. grid (8, 128, 2), 256 thr.
// thread: fg = t&63 -> 8 features f0=fg*8 (one d-slice); q = t>>6 -> 4 w.
// Gathers 6 w-cols x 3 kh x up-to-3 dz of 16B taps straight from global
// (L1/L2-resident); weights in 6.9KB LDS. No main-loop barrier.
// ---------------------------------------------------------------------------
template <bool GELU>
__global__ __launch_bounds__(256, 4) void dwconv_kernel(
    const unsigned short* __restrict__ in,
    const float* __restrict__ wgt,
    const unsigned short* __restrict__ addc,
    unsigned short* __restrict__ outb,
    float* __restrict__ outf) {
  __shared__ float wl[27 * 64];
  int t = threadIdx.x;
  for (int i = t; i < 1728; i += 256) {
    int c = i / 27, tap = i % 27;
    wl[tap * 64 + c] = wgt[i];
  }
  __syncthreads();
  int h = blockIdx.y, b = blockIdx.z;
  int fg = t & 63, q = t >> 6;
  int w0 = blockIdx.x * 16 + q * 4;
  int f0 = fg * 8;
  int d = f0 >> 6, cch = f0 & 63;

  float acc[4][8] = {};
#pragma unroll
  for (int kh = 0; kh < 3; kh++) {
    int gh = h + kh - 1;
    if ((unsigned)gh >= 128u) continue;           // block-uniform
    long rbase = (long)(b * 16384 + gh * 128);
#pragma unroll
    for (int kd = 0; kd < 3; kd++) {
      int dz = d + kd - 1;
      if ((unsigned)dz >= 8u) continue;           // 8/64 lanes idle at d-edges
      int fz = dz * 64 + cch;
      // weights for the 3 w-taps of this (kd,kh)
      float wv[3][8];
#pragma unroll
      for (int kw = 0; kw < 3; kw++) {
        int tap = kd * 9 + kh * 3 + kw;
        *(float4*)&wv[kw][0] = *(const float4*)&wl[tap * 64 + cch];
        *(float4*)&wv[kw][4] = *(const float4*)&wl[tap * 64 + cch + 4];
      }
      // issue the 6 column loads (independent -> deep MLP)
      uint4 rr[6];
#pragma unroll
      for (int cc = 0; cc < 6; cc++) {
        int gw = w0 + cc - 1;
        uint4 vv = {0u, 0u, 0u, 0u};
        if ((unsigned)gw < 128u)
          vv = *(const uint4*)&in[(rbase + gw) * 512 + fz];
        rr[cc] = vv;
      }
#pragma unroll
      for (int cc = 0; cc < 6; cc++) {
        const unsigned short* u = (const unsigned short*)&rr[cc];
        float tf[8];
#pragma unroll
        for (int j = 0; j < 8; j++) tf[j] = bf2f(u[j]);
#pragma unroll
        for (int kw = 0; kw < 3; kw++) {
          int s = cc - kw;                        // output col; compile-time
          if (s < 0 || s > 3) continue;
#pragma unroll
          for (int j = 0; j < 8; j++) acc[s][j] += tf[j] * wv[kw][j];
        }
      }
    }
  }
#pragma unroll
  for (int s = 0; s < 4; s++) {
    long row = (long)(b * 16384 + h * 128 + (w0 + s));
    if (GELU) {
      unsigned short o[8];
#pragma unroll
      for (int j = 0; j < 8; j++) o[j] = f2bf(fast_gelu(acc[s][j]));
      *(uint4*)&outb[row * 512 + f0] = *(uint4*)&o[0];
    } else {
      uint4 av = *(const uint4*)&addc[row * 512 + f0];
      const unsigned short* au = (const unsigned short*)&av;
      float o[8];
#pragma unroll
      for (int j = 0; j < 8; j++) o[j] = acc[s][j] + bf2f(au[j]);
      *(float4*)&outf[row * 512 + f0]     = *(float4*)&o[0];
      *(float4*)&outf[row * 512 + f0 + 4] = *(float4*)&o[4];
    }
  }
}

// ---------------------------------------------------------------------------
extern "C" void kernel_launch(void* const* d_in, const int* in_sizes, int n_in,
                              void* d_out, int out_size, void* d_ws, size_t ws_size,
                              hipStream_t stream) {
  const float* x   = (const float*)d_in[0];
  const float* Wq  = (const float*)d_in[1];
  const float* Wk  = (const float*)d_in[2];
  const float* Wv  = (const float*)d_in[3];
  const float* rsc = (const float*)d_in[4];
  const float* Wp  = (const float*)d_in[5];
  const float* bp  = (const float*)d_in[6];
  const float* pw1 = (const float*)d_in[7];
  const float* pw2 = (const float*)d_in[8];
  float* out = (float*)d_out;

  char* ws = (char*)d_ws;
  unsigned short* x_bf   = (unsigned short*)(ws + 0);            // 33,554,432
  unsigned short* v      = (unsigned short*)(ws + 33554432);     // 33,554,432
  unsigned short* out_c  = (unsigned short*)(ws + 67108864);     // 33,554,432
  float*          Gp     = (float*)(ws + 100663296);             // 33,554,432
  unsigned short* Wcat_t = (unsigned short*)(ws + 167772160);    // 1,572,864
  unsigned short* Wp_t   = (unsigned short*)(ws + 169345024);    // 524,288
  float*          ss     = (float*)(ws + 169869312);             // 8,192
  float*          G      = (float*)(ws + 169877504);             // 524,288
  unsigned short* Abd    = (unsigned short*)(ws + 170401792);    // 1,048,576
  unsigned short* Mt     = (unsigned short*)(ws + 171450368);    // 1,048,576
  unsigned short* p1     = x_bf;  // x_bf dead after v_gemm

  hipMemsetAsync(ss, 0, 8192, stream);
  hipMemsetAsync(Abd, 0, 1048576, stream);

  convert_x<<<8192, 256, 0, stream>>>(x, x_bf);
  prep_w<<<1024, 256, 0, stream>>>(Wq, Wk, Wv, Wp, Wcat_t, Wp_t);

  qk_gram<<<dim3(64, 4, 2), 256, 0, stream>>>(x_bf, Wcat_t, Gp, ss);
  v_gemm<<<dim3(128, 4, 2), 256, 0, stream>>>(x_bf, Wcat_t, v);

  reduce_g<<<512, 256, 0, stream>>>(Gp, G);
  softmax_kernel<<<dim3(4, 2, 1), 256, 0, stream>>>(G, ss, rsc, Abd);

  // Mt[b] = Wp_t @ Abd[b]^T : M=512 N=512 K=512, batch 2
  gemm_lds<<<dim3(4, 4, 2), 256, 0, stream>>>(
      Wp_t, Abd, Mt, nullptr, 512, 512, 512, 512, 0L, 262144L, 262144L);

  // out_c[b] = v @ Mt[b]^T + bp : M=16384 N=512 K=512, batch 2
  gemm_lds<<<dim3(128, 4, 2), 256, 0, stream>>>(
      v, Mt, out_c, bp, 512, 512, 512, 512,
      (long)16384 * 512, 262144L, (long)16384 * 512);

  dwconv_kernel<true><<<dim3(8, 128, 2), 256, 0, stream>>>(
      v, pw1, nullptr, p1, nullptr);
  dwconv_kernel<false><<<dim3(8, 128, 2), 256, 0, stream>>>(
      p1, pw2, out_c, nullptr, out);
}

// Round 8
// 330.659 us; speedup vs baseline: 1.1196x; 1.1196x over previous
//
#include <hip/hip_runtime.h>
#include <math.h>
#include <stdint.h>

// ---------------------------------------------------------------------------
// TransFrame: B=2, H=W=128, D=8, C=64 ; F_IN=F_OUT=512 ; HEADS=4, Dh=128
// Round-8 (= round-7 with NT-builtin types fixed):
//   - qk_gram BK=64 single-buffer (proven 49us; both pipeline variants closed).
//   - conv1 launched right after v_gemm (v L2-hot; p1 aliases dead x_bf).
//   - NT load of read-once fp32 x (convert_x), NT store of write-once fp32
//     out (conv2) -- via ext_vector_type f32x4 (HIP float4 is not a legal
//     operand of __builtin_nontemporal_*).
// ---------------------------------------------------------------------------

using short8  = __attribute__((ext_vector_type(8))) short;
using f32x4   = __attribute__((ext_vector_type(4))) float;

__device__ __forceinline__ float bf2f(unsigned short u) {
  union { unsigned int i; float f; } v; v.i = ((unsigned int)u) << 16; return v.f;
}
__device__ __forceinline__ unsigned short f2bf(float f) {
  union { float f; unsigned int i; } v; v.f = f;
  unsigned int r = v.i + 0x7fffu + ((v.i >> 16) & 1u);
  return (unsigned short)(r >> 16);
}

__device__ __forceinline__ void g2l16(const void* g, void* l) {
  __builtin_amdgcn_global_load_lds(
      (__attribute__((address_space(1))) void*)(unsigned long long)(uintptr_t)g,
      (__attribute__((address_space(3))) void*)(unsigned int)(uintptr_t)l,
      16, 0, 0);
}

// GELU with A&S 7.1.26 erf approximation (|err| <= 1.5e-7, branch-free).
__device__ __forceinline__ float fast_gelu(float x) {
  float y = fabsf(x) * 0.70710678118654752f;
  float t = __builtin_amdgcn_rcpf(1.0f + 0.3275911f * y);
  float p = ((((1.061405429f * t - 1.453152027f) * t + 1.421413741f) * t
              - 0.284496736f) * t + 0.254829592f) * t;
  float er = 1.0f - p * __expf(-y * y);
  er = copysignf(er, x);
  return 0.5f * x * (1.0f + er);
}

// ---------------------------------------------------------------------------
__global__ __launch_bounds__(256) void convert_x(const float* __restrict__ x,
                                                 unsigned short* __restrict__ xb) {
  int i = (blockIdx.x * 256 + threadIdx.x) * 8;
  f32x4 a = __builtin_nontemporal_load((const f32x4*)&x[i]);
  f32x4 b = __builtin_nontemporal_load((const f32x4*)&x[i + 4]);
  ushort4 o0, o1;
  o0.x = f2bf(a[0]); o0.y = f2bf(a[1]); o0.z = f2bf(a[2]); o0.w = f2bf(a[3]);
  o1.x = f2bf(b[0]); o1.y = f2bf(b[1]); o1.z = f2bf(b[2]); o1.w = f2bf(b[3]);
  uint4 o; 
  o.x = *(unsigned*)&o0.x; o.y = *(unsigned*)&o0.z;
  o.z = *(unsigned*)&o1.x; o.w = *(unsigned*)&o1.z;
  *(uint4*)&xb[i] = o;
}

__global__ __launch_bounds__(256) void prep_w(const float* __restrict__ Wq,
                                              const float* __restrict__ Wk,
                                              const float* __restrict__ Wv,
                                              const float* __restrict__ Wp,
                                              unsigned short* __restrict__ Wcat_t,
                                              unsigned short* __restrict__ Wp_t) {
  __shared__ unsigned short Ls[32 * 36];
  int bid = blockIdx.x;
  int mat = bid >> 8, tile = bid & 255;
  int tr = (tile >> 4) * 32, tc = (tile & 15) * 32;
  const float* src = (mat == 0) ? Wq : (mat == 1) ? Wk : (mat == 2) ? Wv : Wp;
  int t = threadIdx.x;
  int r = t >> 3, c4 = (t & 7) * 4;
  float4 v = *(const float4*)&src[(tr + r) * 512 + tc + c4];
  Ls[(c4 + 0) * 36 + r] = f2bf(v.x);
  Ls[(c4 + 1) * 36 + r] = f2bf(v.y);
  Ls[(c4 + 2) * 36 + r] = f2bf(v.z);
  Ls[(c4 + 3) * 36 + r] = f2bf(v.w);
  __syncthreads();
  int rn = t >> 3, ck4 = (t & 7) * 4;
  ushort4 o;
  o.x = Ls[rn * 36 + ck4 + 0]; o.y = Ls[rn * 36 + ck4 + 1];
  o.z = Ls[rn * 36 + ck4 + 2]; o.w = Ls[rn * 36 + ck4 + 3];
  unsigned short* dst = (mat < 3)
      ? &Wcat_t[(long)(mat * 512 + tc + rn) * 512 + tr + ck4]
      : &Wp_t[(long)(tc + rn) * 512 + tr + ck4];
  *(ushort4*)dst = o;
}

// ---------------------------------------------------------------------------
// qk_gram: grid (mt2=64, h=4, b=2). Each block: two 128-row m-tiles.
// BK=64 single-buffer (proven: 49us, 1.1M bank conflicts).
// ---------------------------------------------------------------------------
__global__ __launch_bounds__(256, 2) void qk_gram(
    const unsigned short* __restrict__ x_bf,
    const unsigned short* __restrict__ Wcat_t,
    float* __restrict__ Gp, float* __restrict__ ss) {
  __shared__ unsigned short sh[38912];   // 77,824 B
  unsigned short* As = sh;               // 8192 shorts (128x64)
  unsigned short* B0 = sh + 8192;        // 8192
  unsigned short* B1 = sh + 16384;       // 8192
  const int mt2 = blockIdx.x, h = blockIdx.y, b = blockIdx.z;
  const int t = threadIdx.x;
  const int lane = t & 63, w = t >> 6;
  const int wm = w >> 1, wn = w & 1;
  const int quad = lane >> 4, l16 = lane & 15;
  const int sr = lane >> 3, sc = lane & 7;
  const unsigned short* Bq = Wcat_t + (long)(h * 128) * 512;
  const unsigned short* Bk = Wcat_t + (long)(512 + h * 128) * 512;

  f32x4 g[4][4] = {};   // persistent gram accumulator across both halves

  for (int half = 0; half < 2; half++) {
    const unsigned short* A = x_bf + ((long)b * 16384 + (mt2 * 2 + half) * 128) * 512;
    f32x4 aq[4][4] = {}, ak[4][4] = {};
    for (int k0 = 0; k0 < 512; k0 += 64) {
#pragma unroll
      for (int q = 0; q < 4; q++) {
        int r = q * 32 + w * 8 + sr;
        int ca = (sc ^ sr) * 8;
        g2l16(&A[(long)r * 512 + k0 + ca],  &As[(q * 32 + w * 8) * 64]);
        g2l16(&Bq[(long)r * 512 + k0 + ca], &B0[(q * 32 + w * 8) * 64]);
        g2l16(&Bk[(long)r * 512 + k0 + ca], &B1[(q * 32 + w * 8) * 64]);
      }
      __syncthreads();
#pragma unroll
      for (int kk = 0; kk < 2; kk++) {
        short8 af[4], bq[4], bk[4];
#pragma unroll
        for (int i = 0; i < 4; i++) {
          int r = wm * 64 + i * 16 + l16;
          int s = (kk * 4 + quad) ^ (r & 7);
          af[i] = *(const short8*)&As[r * 64 + s * 8];
        }
#pragma unroll
        for (int j = 0; j < 4; j++) {
          int r = wn * 64 + j * 16 + l16;
          int s = (kk * 4 + quad) ^ (r & 7);
          bq[j] = *(const short8*)&B0[r * 64 + s * 8];
          bk[j] = *(const short8*)&B1[r * 64 + s * 8];
        }
#pragma unroll
        for (int i = 0; i < 4; i++)
#pragma unroll
          for (int j = 0; j < 4; j++) {
            aq[i][j] = __builtin_amdgcn_mfma_f32_16x16x32_bf16(af[i], bq[j], aq[i][j], 0, 0, 0);
            ak[i][j] = __builtin_amdgcn_mfma_f32_16x16x32_bf16(af[i], bk[j], ak[i][j], 0, 0, 0);
          }
      }
      __syncthreads();
    }
    // epilogue: aq[i][j][r] = q[m=wm*64+i*16+quad*4+r][f=wn*64+j*16+l16]
    unsigned short* kT = sh;           // 128 x 136
    unsigned short* qT = sh + 17408;   // 128 x 136
    float* red = (float*)(sh + 34816); // 2048 floats: [0..1023]=q, [1024..]=k
#pragma unroll
    for (int i = 0; i < 4; i++) {
      int mm = wm * 64 + i * 16 + quad * 4;
#pragma unroll
      for (int j = 0; j < 4; j++) {
        int f = wn * 64 + j * 16 + l16;
        ushort4 oq = { f2bf(aq[i][j][0]), f2bf(aq[i][j][1]), f2bf(aq[i][j][2]), f2bf(aq[i][j][3]) };
        ushort4 ok = { f2bf(ak[i][j][0]), f2bf(ak[i][j][1]), f2bf(ak[i][j][2]), f2bf(ak[i][j][3]) };
        *(ushort4*)&qT[f * 136 + mm] = oq;
        *(ushort4*)&kT[f * 136 + mm] = ok;
      }
    }
    // sumsq partials (pre-rounding fp32 acc)
    int grp = wm * 4 + quad;
#pragma unroll
    for (int j = 0; j < 4; j++) {
      float pq = 0.f, pk = 0.f;
#pragma unroll
      for (int i = 0; i < 4; i++)
#pragma unroll
        for (int r = 0; r < 4; r++) { pq += aq[i][j][r] * aq[i][j][r]; pk += ak[i][j][r] * ak[i][j][r]; }
      int col = wn * 64 + j * 16 + l16;
      red[grp * 128 + col] = pq;
      red[1024 + grp * 128 + col] = pk;
    }
    __syncthreads();
    // gram: G[d][e] += sum_m kT[d][m]*qT[e][m], m=0..127 (4 chunks of 32)
#pragma unroll
    for (int kk2 = 0; kk2 < 4; kk2++) {
      short8 afk[4], bfq[4];
#pragma unroll
      for (int i = 0; i < 4; i++)
        afk[i] = *(const short8*)&kT[(wm * 64 + i * 16 + l16) * 136 + kk2 * 32 + quad * 8];
#pragma unroll
      for (int j = 0; j < 4; j++)
        bfq[j] = *(const short8*)&qT[(wn * 64 + j * 16 + l16) * 136 + kk2 * 32 + quad * 8];
#pragma unroll
      for (int i = 0; i < 4; i++)
#pragma unroll
        for (int j = 0; j < 4; j++)
          g[i][j] = __builtin_amdgcn_mfma_f32_16x16x32_bf16(afk[i], bfq[j], g[i][j], 0, 0, 0);
    }
    // finish sumsq for this half
    {
      int sel = t >> 7, col = t & 127;
      float s = 0.f;
#pragma unroll
      for (int g2 = 0; g2 < 8; g2++) s += red[sel * 1024 + g2 * 128 + col];
      atomicAdd(&ss[b * 1024 + sel * 512 + h * 128 + col], s);
    }
    __syncthreads();   // protect kT/qT/red until all reads done before next half's staging
  }

  // store transposed partial: Gt[e][d] (d consecutive in lane -> f32x4)
  float* gp = Gp + (((long)(b * 64 + mt2) * 4 + h) << 14);
#pragma unroll
  for (int i = 0; i < 4; i++) {
    int dd = wm * 64 + i * 16 + quad * 4;
#pragma unroll
    for (int j = 0; j < 4; j++) {
      int e = wn * 64 + j * 16 + l16;
      *(f32x4*)&gp[e * 128 + dd] = g[i][j];
    }
  }
}

// ---------------------------------------------------------------------------
// v_gemm: grid (mt=128, nt=4, b=2). v n-tile, swapped-operand epilogue.
// ---------------------------------------------------------------------------
__global__ __launch_bounds__(256, 3) void v_gemm(
    const unsigned short* __restrict__ x_bf,
    const unsigned short* __restrict__ Wcat_t,
    unsigned short* __restrict__ v) {
  __shared__ unsigned short As[8192];
  __shared__ unsigned short Bs[8192];
  const int mt = blockIdx.x, nt = blockIdx.y, b = blockIdx.z;
  const int t = threadIdx.x;
  const int lane = t & 63, w = t >> 6;
  const int wm = w >> 1, wn = w & 1;
  const int quad = lane >> 4, l16 = lane & 15;
  const int sr = lane >> 3, sc = lane & 7;
  const unsigned short* A  = x_bf + ((long)b * 16384 + mt * 128) * 512;
  const unsigned short* Bt = Wcat_t + (long)(1024 + nt * 128) * 512;

  f32x4 acc[4][4] = {};
  for (int k0 = 0; k0 < 512; k0 += 64) {
#pragma unroll
    for (int q = 0; q < 4; q++) {
      int r = q * 32 + w * 8 + sr;
      int ca = (sc ^ sr) * 8;
      g2l16(&A[(long)r * 512 + k0 + ca],  &As[(q * 32 + w * 8) * 64]);
      g2l16(&Bt[(long)r * 512 + k0 + ca], &Bs[(q * 32 + w * 8) * 64]);
    }
    __syncthreads();
#pragma unroll
    for (int kk = 0; kk < 2; kk++) {
      short8 af[4], bf[4];
#pragma unroll
      for (int i = 0; i < 4; i++) {
        int r = wm * 64 + i * 16 + l16;
        int s = (kk * 4 + quad) ^ (r & 7);
        af[i] = *(const short8*)&As[r * 64 + s * 8];
      }
#pragma unroll
      for (int j = 0; j < 4; j++) {
        int r = wn * 64 + j * 16 + l16;
        int s = (kk * 4 + quad) ^ (r & 7);
        bf[j] = *(const short8*)&Bs[r * 64 + s * 8];
      }
#pragma unroll
      for (int i = 0; i < 4; i++)
#pragma unroll
        for (int j = 0; j < 4; j++)
          acc[i][j] = __builtin_amdgcn_mfma_f32_16x16x32_bf16(bf[j], af[i], acc[i][j], 0, 0, 0);
    }
    __syncthreads();
  }
  unsigned short* vout = v + ((long)b * 16384 + mt * 128) * 512 + nt * 128;
#pragma unroll
  for (int i = 0; i < 4; i++) {
    long rbase = (long)(wm * 64 + i * 16 + l16) * 512;
#pragma unroll
    for (int j = 0; j < 4; j++) {
      int col = wn * 64 + j * 16 + quad * 4;
      uint2 o;
      o.x = (unsigned)f2bf(acc[i][j][0]) | ((unsigned)f2bf(acc[i][j][1]) << 16);
      o.y = (unsigned)f2bf(acc[i][j][2]) | ((unsigned)f2bf(acc[i][j][3]) << 16);
      *(uint2*)&vout[rbase + col] = o;
    }
  }
}

// G(t)[b,h][e][d] = sum over 64 mt2-tiles of Gp
__global__ __launch_bounds__(256) void reduce_g(const float* __restrict__ Gp,
                                                float* __restrict__ G) {
  int i = blockIdx.x * 256 + threadIdx.x;
  int b = i >> 16, h = (i >> 14) & 3, r = i & 16383;
  const float* p = Gp + (((long)b * 256 + h) << 14) + r;
  float s = 0.f;
#pragma unroll 8
  for (int mtv = 0; mtv < 64; mtv++) s += p[(long)mtv * 65536];
  G[i] = s;
}

// ---------------------------------------------------------------------------
// softmax over e of scaled G (input is Gt[e][d]); writes block-diag Abd.
// ---------------------------------------------------------------------------
__global__ __launch_bounds__(256) void softmax_kernel(const float* __restrict__ Gt,
                                                      const float* __restrict__ ss,
                                                      const float* __restrict__ rescale,
                                                      unsigned short* __restrict__ Abd) {
  __shared__ float L[128 * 129];
  __shared__ float rsq[128];
  __shared__ float rsk[128];
  int h = blockIdx.x, b = blockIdx.y;
  int t = threadIdx.x;
  const float* g = Gt + (long)(b * 4 + h) * 16384;
  if (t < 128) rsq[t] = rsqrtf(fmaxf(ss[b * 1024 + h * 128 + t], 1e-24f));
  else { int d = t - 128; rsk[d] = rsqrtf(fmaxf(ss[b * 1024 + 512 + h * 128 + d], 1e-24f)); }
  __syncthreads();
  float rs = rescale[h];
  for (int i = t; i < 16384; i += 256) {
    int e = i >> 7, d = i & 127;           // Gt is e-major
    L[d * 129 + e] = g[i] * rsk[d] * rsq[e] * rs;
  }
  __syncthreads();
  if (t < 128) {
    float* row = &L[t * 129];
    float mx = -1e30f;
    for (int e = 0; e < 128; e++) mx = fmaxf(mx, row[e]);
    float sum = 0.0f;
    for (int e = 0; e < 128; e++) { float ex = __expf(row[e] - mx); row[e] = ex; sum += ex; }
    float inv = 1.0f / sum;
    long abase = (long)b * 262144;
    for (int e = 0; e < 128; e++)
      Abd[abase + (long)(h * 128 + e) * 512 + h * 128 + t] = f2bf(row[e] * inv);
  }
}

// ---------------------------------------------------------------------------
// generic bf16 GEMM: C=A@Bt^T (+bias), swapped epilogue.
// ---------------------------------------------------------------------------
__global__ __launch_bounds__(256, 3) void gemm_lds(
    const unsigned short* __restrict__ A, const unsigned short* __restrict__ Bt,
    unsigned short* __restrict__ C, const float* __restrict__ bias,
    int lda, int ldb, int ldc, int K, long sA, long sB, long sC) {
  __shared__ unsigned short As[128 * 64];
  __shared__ unsigned short Bs[128 * 64];
  const int t = threadIdx.x;
  const int m0 = blockIdx.x * 128, n0 = blockIdx.y * 128;
  A  += (long)blockIdx.z * sA + (long)m0 * lda;
  Bt += (long)blockIdx.z * sB + (long)n0 * ldb;
  C  += (long)blockIdx.z * sC;
  const int lane = t & 63, w = t >> 6;
  const int wm = w >> 1, wn = w & 1;
  const int quad = lane >> 4, l16 = lane & 15;
  const int sr = lane >> 3, sc = lane & 7;

  f32x4 acc[4][4] = {};

  for (int k0 = 0; k0 < K; k0 += 64) {
#pragma unroll
    for (int q = 0; q < 4; q++) {
      int r = q * 32 + w * 8 + sr;
      int ca = (sc ^ sr) * 8;
      g2l16(&A[(long)r * lda + k0 + ca], &As[(q * 32 + w * 8) * 64]);
      g2l16(&Bt[(long)r * ldb + k0 + ca], &Bs[(q * 32 + w * 8) * 64]);
    }
    __syncthreads();
#pragma unroll
    for (int kk = 0; kk < 2; kk++) {
      short8 af[4], bfq[4];
#pragma unroll
      for (int i = 0; i < 4; i++) {
        int r = wm * 64 + i * 16 + l16;
        int s = (kk * 4 + quad) ^ (r & 7);
        af[i] = *(const short8*)&As[r * 64 + s * 8];
      }
#pragma unroll
      for (int j = 0; j < 4; j++) {
        int r = wn * 64 + j * 16 + l16;
        int s = (kk * 4 + quad) ^ (r & 7);
        bfq[j] = *(const short8*)&Bs[r * 64 + s * 8];
      }
#pragma unroll
      for (int i = 0; i < 4; i++)
#pragma unroll
        for (int j = 0; j < 4; j++)
          acc[i][j] = __builtin_amdgcn_mfma_f32_16x16x32_bf16(bfq[j], af[i], acc[i][j], 0, 0, 0);
    }
    __syncthreads();
  }

#pragma unroll
  for (int i = 0; i < 4; i++) {
    long rbase = (long)(m0 + wm * 64 + i * 16 + l16) * ldc;
#pragma unroll
    for (int j = 0; j < 4; j++) {
      int col = n0 + wn * 64 + j * 16 + quad * 4;
      float b0 = 0.f, b1 = 0.f, b2 = 0.f, b3 = 0.f;
      if (bias) { float4 bv = *(const float4*)&bias[col]; b0 = bv.x; b1 = bv.y; b2 = bv.z; b3 = bv.w; }
      uint2 o;
      o.x = (unsigned)f2bf(acc[i][j][0] + b0) | ((unsigned)f2bf(acc[i][j][1] + b1) << 16);
      o.y = (unsigned)f2bf(acc[i][j][2] + b2) | ((unsigned)f2bf(acc[i][j][3] + b3) << 16);
      *(uint2*)&C[rbase + col] = o;
    }
  }
}

// ---------------------------------------------------------------------------
// depthwise 3x3x3 conv, direct-gather version. grid (8, 128, 2), 256 thr.
// thread: fg = t&63 -> 8 features f0=fg*8 (one d-slice); q = t>>6 -> 4 w.
// Gathers 6 w-cols x 3 kh x up-to-3 dz of 16B taps straight from global
// (L1/L2-resident); weights in 6.9KB LDS. No main-loop barrier.
// ---------------------------------------------------------------------------
template <bool GELU>
__global__ __launch_bounds__(256, 4) void dwconv_kernel(
    const unsigned short* __restrict__ in,
    const float* __restrict__ wgt,
    const unsigned short* __restrict__ addc,
    unsigned short* __restrict__ outb,
    float* __restrict__ outf) {
  __shared__ float wl[27 * 64];
  int t = threadIdx.x;
  for (int i = t; i < 1728; i += 256) {
    int c = i / 27, tap = i % 27;
    wl[tap * 64 + c] = wgt[i];
  }
  __syncthreads();
  int h = blockIdx.y, b = blockIdx.z;
  int fg = t & 63, q = t >> 6;
  int w0 = blockIdx.x * 16 + q * 4;
  int f0 = fg * 8;
  int d = f0 >> 6, cch = f0 & 63;

  float acc[4][8] = {};
#pragma unroll
  for (int kh = 0; kh < 3; kh++) {
    int gh = h + kh - 1;
    if ((unsigned)gh >= 128u) continue;           // block-uniform
    long rbase = (long)(b * 16384 + gh * 128);
#pragma unroll
    for (int kd = 0; kd < 3; kd++) {
      int dz = d + kd - 1;
      if ((unsigned)dz >= 8u) continue;           // 8/64 lanes idle at d-edges
      int fz = dz * 64 + cch;
      // weights for the 3 w-taps of this (kd,kh)
      float wv[3][8];
#pragma unroll
      for (int kw = 0; kw < 3; kw++) {
        int tap = kd * 9 + kh * 3 + kw;
        *(float4*)&wv[kw][0] = *(const float4*)&wl[tap * 64 + cch];
        *(float4*)&wv[kw][4] = *(const float4*)&wl[tap * 64 + cch + 4];
      }
      // issue the 6 column loads (independent -> deep MLP)
      uint4 rr[6];
#pragma unroll
      for (int cc = 0; cc < 6; cc++) {
        int gw = w0 + cc - 1;
        uint4 vv = {0u, 0u, 0u, 0u};
        if ((unsigned)gw < 128u)
          vv = *(const uint4*)&in[(rbase + gw) * 512 + fz];
        rr[cc] = vv;
      }
#pragma unroll
      for (int cc = 0; cc < 6; cc++) {
        const unsigned short* u = (const unsigned short*)&rr[cc];
        float tf[8];
#pragma unroll
        for (int j = 0; j < 8; j++) tf[j] = bf2f(u[j]);
#pragma unroll
        for (int kw = 0; kw < 3; kw++) {
          int s = cc - kw;                        // output col; compile-time
          if (s < 0 || s > 3) continue;
#pragma unroll
          for (int j = 0; j < 8; j++) acc[s][j] += tf[j] * wv[kw][j];
        }
      }
    }
  }
#pragma unroll
  for (int s = 0; s < 4; s++) {
    long row = (long)(b * 16384 + h * 128 + (w0 + s));
    if (GELU) {
      unsigned short o[8];
#pragma unroll
      for (int j = 0; j < 8; j++) o[j] = f2bf(fast_gelu(acc[s][j]));
      *(uint4*)&outb[row * 512 + f0] = *(uint4*)&o[0];
    } else {
      uint4 av = *(const uint4*)&addc[row * 512 + f0];
      const unsigned short* au = (const unsigned short*)&av;
      f32x4 o0, o1;
      o0[0] = acc[s][0] + bf2f(au[0]); o0[1] = acc[s][1] + bf2f(au[1]);
      o0[2] = acc[s][2] + bf2f(au[2]); o0[3] = acc[s][3] + bf2f(au[3]);
      o1[0] = acc[s][4] + bf2f(au[4]); o1[1] = acc[s][5] + bf2f(au[5]);
      o1[2] = acc[s][6] + bf2f(au[6]); o1[3] = acc[s][7] + bf2f(au[7]);
      __builtin_nontemporal_store(o0, (f32x4*)&outf[row * 512 + f0]);
      __builtin_nontemporal_store(o1, (f32x4*)&outf[row * 512 + f0 + 4]);
    }
  }
}

// ---------------------------------------------------------------------------
extern "C" void kernel_launch(void* const* d_in, const int* in_sizes, int n_in,
                              void* d_out, int out_size, void* d_ws, size_t ws_size,
                              hipStream_t stream) {
  const float* x   = (const float*)d_in[0];
  const float* Wq  = (const float*)d_in[1];
  const float* Wk  = (const float*)d_in[2];
  const float* Wv  = (const float*)d_in[3];
  const float* rsc = (const float*)d_in[4];
  const float* Wp  = (const float*)d_in[5];
  const float* bp  = (const float*)d_in[6];
  const float* pw1 = (const float*)d_in[7];
  const float* pw2 = (const float*)d_in[8];
  float* out = (float*)d_out;

  char* ws = (char*)d_ws;
  unsigned short* x_bf   = (unsigned short*)(ws + 0);            // 33,554,432
  unsigned short* v      = (unsigned short*)(ws + 33554432);     // 33,554,432
  unsigned short* out_c  = (unsigned short*)(ws + 67108864);     // 33,554,432
  float*          Gp     = (float*)(ws + 100663296);             // 33,554,432
  unsigned short* Wcat_t = (unsigned short*)(ws + 167772160);    // 1,572,864
  unsigned short* Wp_t   = (unsigned short*)(ws + 169345024);    // 524,288
  float*          ss     = (float*)(ws + 169869312);             // 8,192
  float*          G      = (float*)(ws + 169877504);             // 524,288
  unsigned short* Abd    = (unsigned short*)(ws + 170401792);    // 1,048,576
  unsigned short* Mt     = (unsigned short*)(ws + 171450368);    // 1,048,576
  unsigned short* p1     = x_bf;  // x_bf dead after v_gemm

  hipMemsetAsync(ss, 0, 8192, stream);
  hipMemsetAsync(Abd, 0, 1048576, stream);

  convert_x<<<8192, 256, 0, stream>>>(x, x_bf);
  prep_w<<<1024, 256, 0, stream>>>(Wq, Wk, Wv, Wp, Wcat_t, Wp_t);

  qk_gram<<<dim3(64, 4, 2), 256, 0, stream>>>(x_bf, Wcat_t, Gp, ss);
  v_gemm<<<dim3(128, 4, 2), 256, 0, stream>>>(x_bf, Wcat_t, v);

  // conv1 right after v_gemm: v still L2-hot (x_bf/p1 alias legal here).
  dwconv_kernel<true><<<dim3(8, 128, 2), 256, 0, stream>>>(
      v, pw1, nullptr, p1, nullptr);

  reduce_g<<<512, 256, 0, stream>>>(Gp, G);
  softmax_kernel<<<dim3(4, 2, 1), 256, 0, stream>>>(G, ss, rsc, Abd);

  // Mt[b] = Wp_t @ Abd[b]^T : M=512 N=512 K=512, batch 2
  gemm_lds<<<dim3(4, 4, 2), 256, 0, stream>>>(
      Wp_t, Abd, Mt, nullptr, 512, 512, 512, 512, 0L, 262144L, 262144L);

  // out_c[b] = v @ Mt[b]^T + bp : M=16384 N=512 K=512, batch 2
  gemm_lds<<<dim3(128, 4, 2), 256, 0, stream>>>(
      v, Mt, out_c, bp, 512, 512, 512, 512,
      (long)16384 * 512, 262144L, (long)16384 * 512);

  dwconv_kernel<false><<<dim3(8, 128, 2), 256, 0, stream>>>(
      p1, pw2, out_c, nullptr, out);
}